// Round 11
// baseline (402.224 us; speedup 1.0000x reference)
//
#include <hip/hip_runtime.h>
#include <math.h>

#define BB 128
#define MM 35
#define PSZ 224
#define PP (PSZ*PSZ)          // 50176
#define SIGN_PENALTY 10.0f
#define RECON_WEIGHT 0.4f
#define DEFOCUS_RAD 1.0f
#define EPS_F 1e-8f
#define INV2PI 0.15915494309189535f

// CT: 224 = 14*16.  n = 14*n2 + n1; k = 16*k1 + k2.
// Thread n1 owns slots {14n2+n1} == {k2*14+n1} → in-place xs, bf16x2 packed.
// R11: phase GEMM fused into stage1 (pred row in LDS, zern from L2, pixels
// flow GEMM→sincos→LDS with NO persistent regs — R10's spill lesson), both
// defocus states per block via two LDS buffers. 3 launches, no phase buffer.

// ws layout (floats):
//   [1] z_loss  [2] mask^2
//   [2048 ..) partials (stage2 block sums)
//   [T_OFF ..) T [2][B][P][P] packed bf16x2
#define WS_PART_OFF     2048
#define WS_T_OFF        (WS_PART_OFF + 4096)
#define N_PARTIALS      (14*BB*2)
#define S1 232            // stage1 LDS row stride (dwords)
#define S2 17             // stage2 LDS col-tile stride (dwords)

static constexpr float W16R[16] = {
    1.0f, 0.9238795325f, 0.7071067812f, 0.3826834324f, 0.0f,
    -0.3826834324f, -0.7071067812f, -0.9238795325f, -1.0f,
    -0.9238795325f, -0.7071067812f, -0.3826834324f, 0.0f,
    0.3826834324f, 0.7071067812f, 0.9238795325f};
static constexpr float W16I[16] = {
    0.0f, -0.3826834324f, -0.7071067812f, -0.9238795325f, -1.0f,
    -0.9238795325f, -0.7071067812f, -0.3826834324f, 0.0f,
    0.3826834324f, 0.7071067812f, 0.9238795325f, 1.0f,
    0.9238795325f, 0.7071067812f, 0.3826834324f};
static constexpr float W7R[7] = {
    1.0f, 0.6234898019f, -0.2225209340f, -0.9009688679f,
    -0.9009688679f, -0.2225209340f, 0.6234898019f};
static constexpr float W7I[7] = {
    0.0f, -0.7818314825f, -0.9749279122f, -0.4338837391f,
    0.4338837391f, 0.9749279122f, 0.7818314825f};
static constexpr float W14R[7] = {
    1.0f, 0.9009688679f, 0.6234898019f, 0.2225209340f, -0.2225209340f,
    -0.6234898019f, -0.9009688679f};
static constexpr float W14I[7] = {
    0.0f, -0.4338837391f, -0.7818314825f, -0.9749279122f, -0.9749279122f,
    -0.7818314825f, -0.4338837391f};

__device__ __forceinline__ float lincoord(int i) {
    return -1.0f + 2.0f * (float)i / (float)(PSZ - 1);
}
__device__ __forceinline__ void fast_sincos(float x, float* s, float* c) {
    float rv = x * INV2PI;
    rv -= floorf(rv);
    *s = __builtin_amdgcn_sinf(rv);
    *c = __builtin_amdgcn_cosf(rv);
}
__device__ __forceinline__ float2 wexp_neg(float frac) {
    float rv = -frac;
    rv -= floorf(rv);
    return make_float2(__builtin_amdgcn_cosf(rv), __builtin_amdgcn_sinf(rv));
}
__device__ __forceinline__ unsigned pack_bf2(float a, float b) {
    return ((__float_as_uint(a) + 0x8000u) >> 16) |
           ((__float_as_uint(b) + 0x8000u) & 0xffff0000u);
}
__device__ __forceinline__ float2 unpack_bf2(unsigned v) {
    return make_float2(__uint_as_float(v << 16), __uint_as_float(v & 0xffff0000u));
}
__device__ __forceinline__ float2 cmul(float2 a, float2 b) {
    return make_float2(fmaf(a.x, b.x, -a.y * b.y), fmaf(a.x, b.y, a.y * b.x));
}
__device__ __forceinline__ float2 cmulc(float2 a, float wr, float wi) {
    return make_float2(fmaf(a.x, wr, -a.y * wi), fmaf(a.x, wi, a.y * wr));
}
__device__ __forceinline__ float2 cadd(float2 a, float2 b) {
    return make_float2(a.x + b.x, a.y + b.y);
}
__device__ __forceinline__ float2 csub(float2 a, float2 b) {
    return make_float2(a.x - b.x, a.y - b.y);
}
__device__ __forceinline__ void cfma(float& acc, float c, float v) {
    if (c == 0.f) return;
    if (c == 1.f)  { acc += v; return; }
    if (c == -1.f) { acc -= v; return; }
    acc = fmaf(c, v, acc);
}

// 8-pt forward DFT via conjugate-symmetric pairs.
__device__ __forceinline__ void dft8_sym(const float2* u, float2* X) {
    float2 a1 = cadd(u[1], u[7]), b1 = csub(u[1], u[7]);
    float2 a2 = cadd(u[2], u[6]), b2 = csub(u[2], u[6]);
    float2 a3 = cadd(u[3], u[5]), b3 = csub(u[3], u[5]);
    float2 s04 = cadd(u[0], u[4]), d04 = csub(u[0], u[4]);
    X[0] = cadd(cadd(s04, a1), cadd(a2, a3));
    X[4] = cadd(csub(s04, a1), csub(a2, a3));
    {
        float2 p = csub(s04, a2);
        float2 q = csub(b1, b3);
        X[2] = make_float2(p.x + q.y, p.y - q.x);
        X[6] = make_float2(p.x - q.y, p.y + q.x);
    }
#pragma unroll
    for (int m = 1; m <= 3; m += 2) {
        float Px = d04.x, Py = d04.y, Qx = 0.f, Qy = 0.f;
#pragma unroll
        for (int n = 1; n <= 3; n++) {
            const float cR = W16R[(2 * n * m) & 15], cI = W16I[(2 * n * m) & 15];
            const float2 a = (n == 1) ? a1 : (n == 2) ? a2 : a3;
            const float2 b = (n == 1) ? b1 : (n == 2) ? b2 : b3;
            cfma(Px, cR, a.x); cfma(Py, cR, a.y);
            cfma(Qx, cI, b.x); cfma(Qy, cI, b.y);
        }
        X[m]     = make_float2(Px - Qy, Py + Qx);
        X[8 - m] = make_float2(Px + Qy, Py - Qx);
    }
}

// 7-pt forward DFT via conjugate-symmetric pairs.
__device__ __forceinline__ void dft7_sym(const float2* x, float2* X) {
    float2 a1 = cadd(x[1], x[6]), b1 = csub(x[1], x[6]);
    float2 a2 = cadd(x[2], x[5]), b2 = csub(x[2], x[5]);
    float2 a3 = cadd(x[3], x[4]), b3 = csub(x[3], x[4]);
    X[0] = cadd(cadd(x[0], a1), cadd(a2, a3));
#pragma unroll
    for (int k = 1; k <= 3; k++) {
        float Px = x[0].x, Py = x[0].y, Qx = 0.f, Qy = 0.f;
#pragma unroll
        for (int n = 1; n <= 3; n++) {
            const float cR = W7R[(n * k) % 7], cI = W7I[(n * k) % 7];
            const float2 a = (n == 1) ? a1 : (n == 2) ? a2 : a3;
            const float2 b = (n == 1) ? b1 : (n == 2) ? b2 : b3;
            cfma(Px, cR, a.x); cfma(Py, cR, a.y);
            cfma(Qx, cI, b.x); cfma(Qy, cI, b.y);
        }
        X[k]     = make_float2(Px - Qy, Py + Qx);
        X[7 - k] = make_float2(Px + Qy, Py - Qx);
    }
}

// Inner 224-split: 16-pt DFT (radix-2 + sym-8) + W224^{n1*k} twiddle, in-place.
__device__ __forceinline__ void inner16_sym(unsigned* __restrict__ xbuf,
                                            int base, int mul, int n1) {
    float2 x[16];
#pragma unroll
    for (int n = 0; n < 16; n++) x[n] = unpack_bf2(xbuf[base + (14 * n) * mul]);
    float2 u[8], v[8];
#pragma unroll
    for (int n = 0; n < 8; n++) {
        u[n] = cadd(x[n], x[n + 8]);
        float2 w = csub(x[n], x[n + 8]);
        v[n] = (n == 0) ? w : cmulc(w, W16R[n], W16I[n]);
    }
    float2 u1w = wexp_neg((float)n1 * (1.0f / 224.0f));
    float2 u2w = wexp_neg((float)n1 * (1.0f / 112.0f));
    {
        float2 Xe[8];
        dft8_sym(u, Xe);
        float2 cur = make_float2(1.f, 0.f);
#pragma unroll
        for (int m = 0; m < 8; m++) {
            float2 z = (m == 0) ? Xe[0] : cmul(Xe[m], cur);
            xbuf[base + (14 * (2 * m)) * mul] = pack_bf2(z.x, z.y);
            cur = cmul(cur, u2w);
        }
    }
    {
        float2 Xo[8];
        dft8_sym(v, Xo);
        float2 cur = u1w;
#pragma unroll
        for (int m = 0; m < 8; m++) {
            float2 z = cmul(Xo[m], cur);
            xbuf[base + (14 * (2 * m + 1)) * mul] = pack_bf2(z.x, z.y);
            cur = cmul(cur, u2w);
        }
    }
}

// outer 14-pt (sym 2x7) from LDS row xr (stride 1 dword), writes T row
__device__ __forceinline__ void outer14_T(const unsigned* __restrict__ xr,
                                          unsigned* __restrict__ Trow, int k2) {
    float2 e[7], E[7], O[7];
#pragma unroll
    for (int n = 0; n < 7; n++) e[n] = unpack_bf2(xr[2 * n]);
    dft7_sym(e, E);
#pragma unroll
    for (int n = 0; n < 7; n++) e[n] = unpack_bf2(xr[2 * n + 1]);
    dft7_sym(e, O);
#pragma unroll
    for (int k1 = 0; k1 < 7; k1++) {
        float2 op = (k1 == 0) ? O[0] : cmulc(O[k1], W14R[k1], W14I[k1]);
        float2 s = cadd(E[k1], op), q = csub(E[k1], op);
        Trow[16 * k1 + k2]       = pack_bf2(s.x, s.y);
        Trow[16 * (k1 + 7) + k2] = pack_bf2(q.x, q.y);
    }
}

// ---------------- stage 1 (fused): phase GEMM + pupil + row DFTs, both d ----
// grid (14, BB). Block (0,0) additionally computes zloss + mask^2.
__global__ __launch_bounds__(256, 5) void k_stage1(const float* __restrict__ pred,
                                                   const float* __restrict__ target,
                                                   const float* __restrict__ zern,
                                                   const float* __restrict__ mask,
                                                   unsigned* __restrict__ T,
                                                   float* __restrict__ ws) {
    __shared__ unsigned xs0[16 * S1];
    __shared__ unsigned xs1[16 * S1];
    __shared__ float pred_s[MM];
    __shared__ float red[256];
    int h0 = blockIdx.x * 16;
    int b = blockIdx.y;
    int t = threadIdx.x;

    if (t < MM) pred_s[t] = pred[b * MM + t];

    // special block: zloss + mask^2 (results consumed by later kernels)
    if (blockIdx.x == 0 && blockIdx.y == 0) {
        float sz = 0.f, sm = 0.f;
        for (int i = t; i < BB * MM; i += 256) {
            float p = pred[i], tg = target[i];
            float dd = p - tg;
            float w = (p * tg < 0.f) ? SIGN_PENALTY : 1.f;
            sz = fmaf(dd * dd, w, sz);
        }
        const float4* m4 = (const float4*)mask;
        for (int i = t; i < PP / 4; i += 256) {
            float4 v = m4[i];
            sm = fmaf(v.x, v.x, sm); sm = fmaf(v.y, v.y, sm);
            sm = fmaf(v.z, v.z, sm); sm = fmaf(v.w, v.w, sm);
        }
#pragma unroll
        for (int off = 32; off > 0; off >>= 1) {
            sz += __shfl_down(sz, off, 64);
            sm += __shfl_down(sm, off, 64);
        }
        if ((t & 63) == 0) { red[t >> 6] = sz; red[4 + (t >> 6)] = sm; }
        __syncthreads();
        if (t == 0) {
            ws[1] = (red[0] + red[1] + red[2] + red[3]) / (float)(BB * MM);
            ws[2] = red[4] + red[5] + red[6] + red[7];
        }
    }
    __syncthreads();   // pred_s ready (and special block's red[] use done)

    // phase GEMM -> pupil (both defocus states), pixels streamed, no persistence
    const float* zb = zern + (size_t)h0 * PSZ;
    const float* mb = mask + (size_t)h0 * PSZ;
#pragma unroll
    for (int i = 0; i < 14; i++) {
        int idx = t + 256 * i;
        float ph = 0.f;
        for (int m = 0; m < MM; m++)
            ph = fmaf(pred_s[m], zb[(size_t)m * PP + idx], ph);
        float mk = mb[idx];
        ph *= mk;
        int r = idx / PSZ, w = idx - r * PSZ;
        float sn, cs;
        fast_sincos(ph, &sn, &cs);
        xs0[r * S1 + w] = pack_bf2(mk * cs, mk * sn);
        float vy = lincoord(h0 + r), vx = lincoord(w);
        float ph1 = ph + DEFOCUS_RAD * (2.f * (vx * vx + vy * vy) - 1.f);
        fast_sincos(ph1, &sn, &cs);
        xs1[r * S1 + w] = pack_bf2(mk * cs, mk * sn);
    }
    __syncthreads();

    if (t < 224) {                    // inner: 16 rows x 14 n1, in-place, both d
        int r = t / 14, n1 = t - r * 14;
        inner16_sym(xs0, r * S1 + n1, 1, n1);
        inner16_sym(xs1, r * S1 + n1, 1, n1);
    }
    __syncthreads();

    {                                 // outer: 16 rows x 16 k2, both d
        int r = t >> 4, k2 = t & 15;
        unsigned* Trow0 = T + ((size_t)b * PSZ + (h0 + r)) * PSZ;
        outer14_T(xs0 + r * S1 + k2 * 14, Trow0, k2);
        unsigned* Trow1 = Trow0 + (size_t)BB * PP;
        outer14_T(xs1 + r * S1 + k2 * 14, Trow1, k2);
    }
}

// ---------------- stage 2: column DFTs + in-register psf loss ----------------
__global__ __launch_bounds__(256, 6) void k_stage2(const unsigned* __restrict__ T,
                                                   const float* __restrict__ psfs,
                                                   const float* __restrict__ ws,
                                                   float* __restrict__ partials) {
    __shared__ unsigned xs[224 * S2];
    __shared__ float red[4];
    int tile = blockIdx.x, b = blockIdx.y, d = blockIdx.z;
    int img = d * BB + b;
    int col0 = tile * 16;
    int t = threadIdx.x;
    int k2o = t >> 4, c = t & 15;

    const unsigned* Tbase = T + (size_t)img * PP + col0;
    const float* inp = psfs + ((size_t)b * 2 + d) * PP;
    int scol = 16 * ((tile + 7) % 14) + c;
    float pf[14];
#pragma unroll
    for (int i = 0; i < 14; i++) {
        int idx = t + 256 * i;
        int h = idx >> 4, cc = idx & 15;
        xs[h * S2 + cc] = Tbase[(size_t)h * PSZ + cc];
    }
#pragma unroll
    for (int j = 0; j < 7; j++) {
        pf[j]     = inp[(size_t)(112 + 16 * j + k2o) * PSZ + scol];
        pf[j + 7] = inp[(size_t)(16 * j + k2o) * PSZ + scol];
    }
    __syncthreads();

    if (t < 224) {                    // inner: 14 n1 x 16 c, in-place
        int n1 = t >> 4, cc = t & 15;
        inner16_sym(xs, n1 * S2 + cc, S2, n1);
    }
    __syncthreads();

    float m2 = ws[2];
    float inv_denom = 1.f / (m2 * (float)PP + EPS_F);  // Parseval denominator

    float lsum = 0.f;
    {                                 // outer: 16 k2 x 16 c, loss in-register
        float2 e[7], E[7], O[7];
#pragma unroll
        for (int n = 0; n < 7; n++) e[n] = unpack_bf2(xs[(k2o * 14 + 2 * n) * S2 + c]);
        dft7_sym(e, E);
#pragma unroll
        for (int n = 0; n < 7; n++) e[n] = unpack_bf2(xs[(k2o * 14 + 2 * n + 1) * S2 + c]);
        dft7_sym(e, O);
#pragma unroll
        for (int k1 = 0; k1 < 7; k1++) {
            float2 op = (k1 == 0) ? O[0] : cmulc(O[k1], W14R[k1], W14I[k1]);
            float2 s = cadd(E[k1], op), q = csub(E[k1], op);
            float ds = fmaf(s.x, s.x, s.y * s.y) * inv_denom - pf[k1];
            float dq = fmaf(q.x, q.x, q.y * q.y) * inv_denom - pf[k1 + 7];
            lsum = fmaf(ds, ds, lsum);
            lsum = fmaf(dq, dq, lsum);
        }
    }
#pragma unroll
    for (int off = 32; off > 0; off >>= 1)
        lsum += __shfl_down(lsum, off, 64);
    if ((t & 63) == 0) red[t >> 6] = lsum;
    __syncthreads();
    if (t == 0)
        partials[(blockIdx.z * BB + blockIdx.y) * 14 + blockIdx.x] =
            red[0] + red[1] + red[2] + red[3];
}

// ---------------- final ----------------
__global__ void k_final(const float* __restrict__ ws,
                        const float* __restrict__ partials,
                        float* __restrict__ out) {
    __shared__ float red[256];
    float s = 0.f;
    for (int i = threadIdx.x; i < N_PARTIALS; i += 256) s += partials[i];
    red[threadIdx.x] = s;
    __syncthreads();
    for (int st = 128; st > 0; st >>= 1) {
        if (threadIdx.x < st) red[threadIdx.x] += red[threadIdx.x + st];
        __syncthreads();
    }
    if (threadIdx.x == 0) {
        float recon = red[0] / (float)((size_t)BB * PP);
        out[0] = ws[1] + RECON_WEIGHT * recon;
    }
}

extern "C" void kernel_launch(void* const* d_in, const int* in_sizes, int n_in,
                              void* d_out, int out_size, void* d_ws, size_t ws_size,
                              hipStream_t stream) {
    const float* pred   = (const float*)d_in[0];
    const float* target = (const float*)d_in[1];
    const float* psfs   = (const float*)d_in[2];
    const float* zern   = (const float*)d_in[3];
    const float* mask   = (const float*)d_in[4];

    float*    ws       = (float*)d_ws;
    float*    partials = ws + WS_PART_OFF;
    unsigned* T        = (unsigned*)(ws + WS_T_OFF);
    float*    out      = (float*)d_out;

    k_stage1<<<dim3(14, BB), 256, 0, stream>>>(pred, target, zern, mask, T, ws);
    k_stage2<<<dim3(14, BB, 2), 256, 0, stream>>>(T, psfs, ws, partials);
    k_final<<<1, 256, 0, stream>>>(ws, partials, out);
}

// Round 12
// 180.301 us; speedup vs baseline: 2.2308x; 2.2308x over previous
//
#include <hip/hip_runtime.h>
#include <math.h>

#define BB 128
#define MM 35
#define PSZ 224
#define PP (PSZ*PSZ)          // 50176
#define SIGN_PENALTY 10.0f
#define RECON_WEIGHT 0.4f
#define DEFOCUS_RAD 1.0f
#define EPS_F 1e-8f
#define INV2PI 0.15915494309189535f

// CT: 224 = 14*16.  n = 14*n2 + n1; k = 16*k1 + k2.
// Thread n1 owns slots {14n2+n1} == {k2*14+n1} → in-place xs, bf16x2 packed.
// R12 = consolidation of proven-best pieces:
//   k_phase: R9 (32-batch GEMM; zloss/mask^2 folded)
//   k_stage1: R9 (per-d grid, streaming, no persistent regs — spill-safe)
//   k_stage2: R10 (in-register psf loss, 2 barriers, shuffle reduce)
// Spill rule (R10/R11): >~32 floats of cross-phase state per thread = scratch
// spill = +100s of MB HBM. Atomic rule (R5-R7): no same-address finale atomics.

// ws layout (floats):
//   [1] z_loss  [2..4] mask^2 partials (3)
//   [2048 ..) phase [B][P][P] — dead after stage1; partials alias it
//   [T_OFF ..) T [2][B][P][P] packed bf16x2
#define WS_PHASE_OFF    2048
#define WS_T_OFF        (WS_PHASE_OFF + BB*PP)
#define N_PARTIALS      (14*BB*2)
#define S1 232            // stage1 LDS row stride (dwords)
#define S2 17             // stage2 LDS col-tile stride (dwords)

static constexpr float W16R[16] = {
    1.0f, 0.9238795325f, 0.7071067812f, 0.3826834324f, 0.0f,
    -0.3826834324f, -0.7071067812f, -0.9238795325f, -1.0f,
    -0.9238795325f, -0.7071067812f, -0.3826834324f, 0.0f,
    0.3826834324f, 0.7071067812f, 0.9238795325f};
static constexpr float W16I[16] = {
    0.0f, -0.3826834324f, -0.7071067812f, -0.9238795325f, -1.0f,
    -0.9238795325f, -0.7071067812f, -0.3826834324f, 0.0f,
    0.3826834324f, 0.7071067812f, 0.9238795325f, 1.0f,
    0.9238795325f, 0.7071067812f, 0.3826834324f};
static constexpr float W7R[7] = {
    1.0f, 0.6234898019f, -0.2225209340f, -0.9009688679f,
    -0.9009688679f, -0.2225209340f, 0.6234898019f};
static constexpr float W7I[7] = {
    0.0f, -0.7818314825f, -0.9749279122f, -0.4338837391f,
    0.4338837391f, 0.9749279122f, 0.7818314825f};
static constexpr float W14R[7] = {
    1.0f, 0.9009688679f, 0.6234898019f, 0.2225209340f, -0.2225209340f,
    -0.6234898019f, -0.9009688679f};
static constexpr float W14I[7] = {
    0.0f, -0.4338837391f, -0.7818314825f, -0.9749279122f, -0.9749279122f,
    -0.7818314825f, -0.4338837391f};

__device__ __forceinline__ float lincoord(int i) {
    return -1.0f + 2.0f * (float)i / (float)(PSZ - 1);
}
__device__ __forceinline__ void fast_sincos(float x, float* s, float* c) {
    float rv = x * INV2PI;
    rv -= floorf(rv);
    *s = __builtin_amdgcn_sinf(rv);
    *c = __builtin_amdgcn_cosf(rv);
}
__device__ __forceinline__ float2 wexp_neg(float frac) {
    float rv = -frac;
    rv -= floorf(rv);
    return make_float2(__builtin_amdgcn_cosf(rv), __builtin_amdgcn_sinf(rv));
}
__device__ __forceinline__ unsigned pack_bf2(float a, float b) {
    return ((__float_as_uint(a) + 0x8000u) >> 16) |
           ((__float_as_uint(b) + 0x8000u) & 0xffff0000u);
}
__device__ __forceinline__ float2 unpack_bf2(unsigned v) {
    return make_float2(__uint_as_float(v << 16), __uint_as_float(v & 0xffff0000u));
}
__device__ __forceinline__ float2 cmul(float2 a, float2 b) {
    return make_float2(fmaf(a.x, b.x, -a.y * b.y), fmaf(a.x, b.y, a.y * b.x));
}
__device__ __forceinline__ float2 cmulc(float2 a, float wr, float wi) {
    return make_float2(fmaf(a.x, wr, -a.y * wi), fmaf(a.x, wi, a.y * wr));
}
__device__ __forceinline__ float2 cadd(float2 a, float2 b) {
    return make_float2(a.x + b.x, a.y + b.y);
}
__device__ __forceinline__ float2 csub(float2 a, float2 b) {
    return make_float2(a.x - b.x, a.y - b.y);
}
__device__ __forceinline__ void cfma(float& acc, float c, float v) {
    if (c == 0.f) return;
    if (c == 1.f)  { acc += v; return; }
    if (c == -1.f) { acc -= v; return; }
    acc = fmaf(c, v, acc);
}

// 8-pt forward DFT via conjugate-symmetric pairs.
__device__ __forceinline__ void dft8_sym(const float2* u, float2* X) {
    float2 a1 = cadd(u[1], u[7]), b1 = csub(u[1], u[7]);
    float2 a2 = cadd(u[2], u[6]), b2 = csub(u[2], u[6]);
    float2 a3 = cadd(u[3], u[5]), b3 = csub(u[3], u[5]);
    float2 s04 = cadd(u[0], u[4]), d04 = csub(u[0], u[4]);
    X[0] = cadd(cadd(s04, a1), cadd(a2, a3));
    X[4] = cadd(csub(s04, a1), csub(a2, a3));
    {
        float2 p = csub(s04, a2);
        float2 q = csub(b1, b3);
        X[2] = make_float2(p.x + q.y, p.y - q.x);
        X[6] = make_float2(p.x - q.y, p.y + q.x);
    }
#pragma unroll
    for (int m = 1; m <= 3; m += 2) {
        float Px = d04.x, Py = d04.y, Qx = 0.f, Qy = 0.f;
#pragma unroll
        for (int n = 1; n <= 3; n++) {
            const float cR = W16R[(2 * n * m) & 15], cI = W16I[(2 * n * m) & 15];
            const float2 a = (n == 1) ? a1 : (n == 2) ? a2 : a3;
            const float2 b = (n == 1) ? b1 : (n == 2) ? b2 : b3;
            cfma(Px, cR, a.x); cfma(Py, cR, a.y);
            cfma(Qx, cI, b.x); cfma(Qy, cI, b.y);
        }
        X[m]     = make_float2(Px - Qy, Py + Qx);
        X[8 - m] = make_float2(Px + Qy, Py - Qx);
    }
}

// 7-pt forward DFT via conjugate-symmetric pairs.
__device__ __forceinline__ void dft7_sym(const float2* x, float2* X) {
    float2 a1 = cadd(x[1], x[6]), b1 = csub(x[1], x[6]);
    float2 a2 = cadd(x[2], x[5]), b2 = csub(x[2], x[5]);
    float2 a3 = cadd(x[3], x[4]), b3 = csub(x[3], x[4]);
    X[0] = cadd(cadd(x[0], a1), cadd(a2, a3));
#pragma unroll
    for (int k = 1; k <= 3; k++) {
        float Px = x[0].x, Py = x[0].y, Qx = 0.f, Qy = 0.f;
#pragma unroll
        for (int n = 1; n <= 3; n++) {
            const float cR = W7R[(n * k) % 7], cI = W7I[(n * k) % 7];
            const float2 a = (n == 1) ? a1 : (n == 2) ? a2 : a3;
            const float2 b = (n == 1) ? b1 : (n == 2) ? b2 : b3;
            cfma(Px, cR, a.x); cfma(Py, cR, a.y);
            cfma(Qx, cI, b.x); cfma(Qy, cI, b.y);
        }
        X[k]     = make_float2(Px - Qy, Py + Qx);
        X[7 - k] = make_float2(Px + Qy, Py - Qx);
    }
}

// Inner 224-split: 16-pt DFT (radix-2 + sym-8) + W224^{n1*k} twiddle, in-place.
__device__ __forceinline__ void inner16_sym(unsigned* __restrict__ xbuf,
                                            int base, int mul, int n1) {
    float2 x[16];
#pragma unroll
    for (int n = 0; n < 16; n++) x[n] = unpack_bf2(xbuf[base + (14 * n) * mul]);
    float2 u[8], v[8];
#pragma unroll
    for (int n = 0; n < 8; n++) {
        u[n] = cadd(x[n], x[n + 8]);
        float2 w = csub(x[n], x[n + 8]);
        v[n] = (n == 0) ? w : cmulc(w, W16R[n], W16I[n]);
    }
    float2 u1w = wexp_neg((float)n1 * (1.0f / 224.0f));
    float2 u2w = wexp_neg((float)n1 * (1.0f / 112.0f));
    {
        float2 Xe[8];
        dft8_sym(u, Xe);
        float2 cur = make_float2(1.f, 0.f);
#pragma unroll
        for (int m = 0; m < 8; m++) {
            float2 z = (m == 0) ? Xe[0] : cmul(Xe[m], cur);
            xbuf[base + (14 * (2 * m)) * mul] = pack_bf2(z.x, z.y);
            cur = cmul(cur, u2w);
        }
    }
    {
        float2 Xo[8];
        dft8_sym(v, Xo);
        float2 cur = u1w;
#pragma unroll
        for (int m = 0; m < 8; m++) {
            float2 z = cmul(Xo[m], cur);
            xbuf[base + (14 * (2 * m + 1)) * mul] = pack_bf2(z.x, z.y);
            cur = cmul(cur, u2w);
        }
    }
}

// ---------------- k_phase: grid (197, 4). x<196: phase GEMM (32 b each).
// x==196: y0 zloss, y1..3 mask^2 thirds.
__global__ __launch_bounds__(256) void k_phase(const float* __restrict__ pred,
                                               const float* __restrict__ target,
                                               const float* __restrict__ zern,
                                               const float* __restrict__ mask,
                                               float* __restrict__ phase,
                                               float* __restrict__ ws) {
    __shared__ float pl[32 * MM];
    __shared__ float red[256];
    int t = threadIdx.x;
    if (blockIdx.x == 196) {
        int y = blockIdx.y;
        float s = 0.f;
        if (y == 0) {
            for (int i = t; i < BB * MM; i += 256) {
                float p = pred[i], tg = target[i];
                float dd = p - tg;
                float w = (p * tg < 0.f) ? SIGN_PENALTY : 1.f;
                s = fmaf(dd * dd, w, s);
            }
        } else {
            const int F4 = PP / 4;
            int st = (y - 1) * 4182;
            int en = (y == 3) ? F4 : st + 4182;
            const float4* m4 = (const float4*)mask;
            for (int i = st + t; i < en; i += 256) {
                float4 v = m4[i];
                s = fmaf(v.x, v.x, s); s = fmaf(v.y, v.y, s);
                s = fmaf(v.z, v.z, s); s = fmaf(v.w, v.w, s);
            }
        }
        red[t] = s;
        __syncthreads();
        for (int st = 128; st > 0; st >>= 1) {
            if (t < st) red[t] += red[t + st];
            __syncthreads();
        }
        if (t == 0) {
            if (y == 0) ws[1] = red[0] / (float)(BB * MM);
            else        ws[1 + y] = red[0];
        }
        return;
    }
    int bg = blockIdx.y;
    for (int i = t; i < 32 * MM; i += 256) {
        int j = i / MM, m = i % MM;
        pl[i] = pred[(bg * 32 + j) * MM + m];
    }
    __syncthreads();
    int pix = blockIdx.x * 256 + t;
    float acc[32];
#pragma unroll
    for (int j = 0; j < 32; j++) acc[j] = 0.f;
    for (int m = 0; m < MM; m++) {
        float z = zern[m * PP + pix];
#pragma unroll
        for (int j = 0; j < 32; j++) acc[j] = fmaf(pl[j * MM + m], z, acc[j]);
    }
    float mk = mask[pix];
#pragma unroll
    for (int j = 0; j < 32; j++) phase[(size_t)(bg * 32 + j) * PP + pix] = acc[j] * mk;
}

// ---------------- stage 1: row DFTs (sym inner + sym 2x7 outer), per-d -------
__global__ __launch_bounds__(256, 6) void k_stage1(const float* __restrict__ phase,
                                                   const float* __restrict__ mask,
                                                   unsigned* __restrict__ T) {
    __shared__ unsigned xs[16 * S1];
    int h0 = blockIdx.x * 16;
    int b = blockIdx.y, d = blockIdx.z;
    int t = threadIdx.x;

    const float* ph_base = phase + (size_t)b * PP + (size_t)h0 * PSZ;
    for (int idx = t; idx < 16 * PSZ; idx += 256) {
        int r = idx / PSZ, w = idx - r * PSZ;
        float ph = ph_base[r * PSZ + w];
        if (d) {
            float vy = lincoord(h0 + r), vx = lincoord(w);
            ph += DEFOCUS_RAD * (2.f * (vx * vx + vy * vy) - 1.f);
        }
        float mk = mask[(h0 + r) * PSZ + w];
        float sn, cs;
        fast_sincos(ph, &sn, &cs);
        xs[r * S1 + w] = pack_bf2(mk * cs, mk * sn);
    }
    __syncthreads();

    if (t < 224) {                    // inner: 16 rows x 14 n1, in-place
        int r = t / 14, n1 = t - r * 14;
        inner16_sym(xs, r * S1 + n1, 1, n1);
    }
    __syncthreads();

    {                                 // outer: 16 rows x 16 k2, sym 2x7
        int r = t >> 4, k2 = t & 15;
        const unsigned* xr = xs + r * S1 + k2 * 14;
        int img = d * BB + b;
        unsigned* Trow = T + ((size_t)img * PSZ + (h0 + r)) * PSZ;
        float2 e[7], E[7], O[7];
#pragma unroll
        for (int n = 0; n < 7; n++) e[n] = unpack_bf2(xr[2 * n]);
        dft7_sym(e, E);
#pragma unroll
        for (int n = 0; n < 7; n++) e[n] = unpack_bf2(xr[2 * n + 1]);
        dft7_sym(e, O);
#pragma unroll
        for (int k1 = 0; k1 < 7; k1++) {
            float2 op = (k1 == 0) ? O[0] : cmulc(O[k1], W14R[k1], W14I[k1]);
            float2 s = cadd(E[k1], op), q = csub(E[k1], op);
            Trow[16 * k1 + k2]       = pack_bf2(s.x, s.y);
            Trow[16 * (k1 + 7) + k2] = pack_bf2(q.x, q.y);
        }
    }
}

// ---------------- stage 2: column DFTs + in-register psf loss ----------------
// Thread (k2,c) produces psf rows {16k1+k2} at col c — compares against its
// own prefetched inp values; no psf LDS round-trip, 2 barriers.
__global__ __launch_bounds__(256, 6) void k_stage2(const unsigned* __restrict__ T,
                                                   const float* __restrict__ psfs,
                                                   const float* __restrict__ ws,
                                                   float* __restrict__ partials) {
    __shared__ unsigned xs[224 * S2];
    __shared__ float red[4];
    int tile = blockIdx.x, b = blockIdx.y, d = blockIdx.z;
    int img = d * BB + b;
    int col0 = tile * 16;
    int t = threadIdx.x;
    int k2o = t >> 4, c = t & 15;

    const unsigned* Tbase = T + (size_t)img * PP + col0;
    const float* inp = psfs + ((size_t)b * 2 + d) * PP;
    int scol = 16 * ((tile + 7) % 14) + c;
    float pf[14];
#pragma unroll
    for (int i = 0; i < 14; i++) {
        int idx = t + 256 * i;
        int h = idx >> 4, cc = idx & 15;
        xs[h * S2 + cc] = Tbase[(size_t)h * PSZ + cc];
    }
#pragma unroll
    for (int j = 0; j < 7; j++) {
        pf[j]     = inp[(size_t)(112 + 16 * j + k2o) * PSZ + scol];
        pf[j + 7] = inp[(size_t)(16 * j + k2o) * PSZ + scol];
    }
    __syncthreads();

    if (t < 224) {                    // inner: 14 n1 x 16 c, in-place
        int n1 = t >> 4, cc = t & 15;
        inner16_sym(xs, n1 * S2 + cc, S2, n1);
    }
    __syncthreads();

    float m2 = ws[2] + ws[3] + ws[4];
    float inv_denom = 1.f / (m2 * (float)PP + EPS_F);  // Parseval denominator

    float lsum = 0.f;
    {                                 // outer: 16 k2 x 16 c, loss in-register
        float2 e[7], E[7], O[7];
#pragma unroll
        for (int n = 0; n < 7; n++) e[n] = unpack_bf2(xs[(k2o * 14 + 2 * n) * S2 + c]);
        dft7_sym(e, E);
#pragma unroll
        for (int n = 0; n < 7; n++) e[n] = unpack_bf2(xs[(k2o * 14 + 2 * n + 1) * S2 + c]);
        dft7_sym(e, O);
#pragma unroll
        for (int k1 = 0; k1 < 7; k1++) {
            float2 op = (k1 == 0) ? O[0] : cmulc(O[k1], W14R[k1], W14I[k1]);
            float2 s = cadd(E[k1], op), q = csub(E[k1], op);
            float ds = fmaf(s.x, s.x, s.y * s.y) * inv_denom - pf[k1];
            float dq = fmaf(q.x, q.x, q.y * q.y) * inv_denom - pf[k1 + 7];
            lsum = fmaf(ds, ds, lsum);
            lsum = fmaf(dq, dq, lsum);
        }
    }
#pragma unroll
    for (int off = 32; off > 0; off >>= 1)
        lsum += __shfl_down(lsum, off, 64);
    if ((t & 63) == 0) red[t >> 6] = lsum;
    __syncthreads();
    if (t == 0)
        partials[(blockIdx.z * BB + blockIdx.y) * 14 + blockIdx.x] =
            red[0] + red[1] + red[2] + red[3];
}

// ---------------- final ----------------
__global__ void k_final(const float* __restrict__ ws,
                        const float* __restrict__ partials,
                        float* __restrict__ out) {
    __shared__ float red[256];
    float s = 0.f;
    for (int i = threadIdx.x; i < N_PARTIALS; i += 256) s += partials[i];
    red[threadIdx.x] = s;
    __syncthreads();
    for (int st = 128; st > 0; st >>= 1) {
        if (threadIdx.x < st) red[threadIdx.x] += red[threadIdx.x + st];
        __syncthreads();
    }
    if (threadIdx.x == 0) {
        float recon = red[0] / (float)((size_t)BB * PP);
        out[0] = ws[1] + RECON_WEIGHT * recon;
    }
}

extern "C" void kernel_launch(void* const* d_in, const int* in_sizes, int n_in,
                              void* d_out, int out_size, void* d_ws, size_t ws_size,
                              hipStream_t stream) {
    const float* pred   = (const float*)d_in[0];
    const float* target = (const float*)d_in[1];
    const float* psfs   = (const float*)d_in[2];
    const float* zern   = (const float*)d_in[3];
    const float* mask   = (const float*)d_in[4];

    float*    ws       = (float*)d_ws;
    float*    phase    = ws + WS_PHASE_OFF;
    float*    partials = ws + WS_PHASE_OFF;   // aliases phase (dead after stage1)
    unsigned* T        = (unsigned*)(ws + WS_T_OFF);
    float*    out      = (float*)d_out;

    k_phase<<<dim3(197, 4), 256, 0, stream>>>(pred, target, zern, mask, phase, ws);
    k_stage1<<<dim3(14, BB, 2), 256, 0, stream>>>(phase, mask, T);
    k_stage2<<<dim3(14, BB, 2), 256, 0, stream>>>(T, psfs, ws, partials);
    k_final<<<1, 256, 0, stream>>>(ws, partials, out);
}